// Round 1
// baseline (769.258 us; speedup 1.0000x reference)
//
#include <hip/hip_runtime.h>

#define NEG (-1e9f)

typedef __attribute__((ext_vector_type(8))) short bf16x8;
typedef __attribute__((ext_vector_type(4))) float f32x4;

static constexpr int Ss = 2048, Dd = 64;

__device__ __forceinline__ unsigned short f2bf(float f) {
  union { float f; unsigned u; } v; v.f = f;
  unsigned r = v.u + 0x7FFF + ((v.u >> 16) & 1);  // RTNE
  return (unsigned short)(r >> 16);
}

// ---------------- prep: K -> bf16 [bh][s][d]; V -> bf16 transposed [bh][d][s] ----------------
__global__ __launch_bounds__(256) void prep_kernel(
    const float* __restrict__ k, const float* __restrict__ v,
    unsigned short* __restrict__ kbf, unsigned short* __restrict__ vtbf) {
  const int tid = threadIdx.x;
  const int bh = blockIdx.x >> 5;
  const int st = blockIdx.x & 31;
  __shared__ unsigned short Vl[64 * 68];
  const size_t base = ((size_t)bh * Ss + (size_t)st * 64) * Dd;
#pragma unroll
  for (int i = 0; i < 4; ++i) {
    int idx4 = tid + i * 256;
    int row = idx4 >> 4, col = (idx4 & 15) * 4;
    float4 f = *(const float4*)(k + base + row * 64 + col);
    ushort4 u;
    u.x = f2bf(f.x); u.y = f2bf(f.y); u.z = f2bf(f.z); u.w = f2bf(f.w);
    *(ushort4*)&kbf[base + row * 64 + col] = u;
    float4 g = *(const float4*)(v + base + row * 64 + col);
    ushort4 w;
    w.x = f2bf(g.x); w.y = f2bf(g.y); w.z = f2bf(g.z); w.w = f2bf(g.w);
    *(ushort4*)&Vl[row * 68 + col] = w;
  }
  __syncthreads();
  const int d = tid >> 2, sb = (tid & 3) * 16;
  bf16x8 a, b;
#pragma unroll
  for (int i = 0; i < 8; ++i) a[i] = (short)Vl[(sb + i) * 68 + d];
#pragma unroll
  for (int i = 0; i < 8; ++i) b[i] = (short)Vl[(sb + 8 + i) * 68 + d];
  unsigned short* vo = vtbf + ((size_t)bh * Dd + d) * Ss + (size_t)st * 64 + sb;
  *(bf16x8*)vo = a;
  *(bf16x8*)(vo + 8) = b;
}

// ---------------- main: swapped-operand MFMA, no barriers ----------------
__global__ __launch_bounds__(256) void attn_kernel(
    const float* __restrict__ q, const unsigned short* __restrict__ kbf,
    const unsigned short* __restrict__ vtbf, const int* __restrict__ mask,
    float* __restrict__ out, float* __restrict__ attn) {
  const int tid = threadIdx.x;
  const int wave = tid >> 6, lane = tid & 63, quad = lane >> 4, ln15 = lane & 15;
  const int bh = blockIdx.x & 31;          // same bh -> same XCD (stride 32 ≡ 0 mod 8)
  const int qt = 31 - (blockIdx.x >> 5);   // big causal blocks dispatched first
  const int b = bh >> 4;                   // H = 16
  const int qloc = wave * 16 + ln15;       // this lane's q row within the 64-row tile
  const int qg = qt * 64 + qloc;           // global q row

  __shared__ unsigned short Plds[64 * 72]; // per-wave 16-row strips, no barrier needed

  // Q fragments (B-operand layout; lane ln15 = q row, quad*8+i = d), scaled by 1/8 (exact pow2)
  bf16x8 qf0, qf1;
  {
    const float* qp = q + ((size_t)bh * Ss + qg) * Dd + quad * 8;
    float4 f0 = *(const float4*)(qp);
    float4 f1 = *(const float4*)(qp + 4);
    float4 f2 = *(const float4*)(qp + 32);
    float4 f3 = *(const float4*)(qp + 36);
    qf0[0] = (short)f2bf(f0.x * 0.125f); qf0[1] = (short)f2bf(f0.y * 0.125f);
    qf0[2] = (short)f2bf(f0.z * 0.125f); qf0[3] = (short)f2bf(f0.w * 0.125f);
    qf0[4] = (short)f2bf(f1.x * 0.125f); qf0[5] = (short)f2bf(f1.y * 0.125f);
    qf0[6] = (short)f2bf(f1.z * 0.125f); qf0[7] = (short)f2bf(f1.w * 0.125f);
    qf1[0] = (short)f2bf(f2.x * 0.125f); qf1[1] = (short)f2bf(f2.y * 0.125f);
    qf1[2] = (short)f2bf(f2.z * 0.125f); qf1[3] = (short)f2bf(f2.w * 0.125f);
    qf1[4] = (short)f2bf(f3.x * 0.125f); qf1[5] = (short)f2bf(f3.y * 0.125f);
    qf1[6] = (short)f2bf(f3.z * 0.125f); qf1[7] = (short)f2bf(f3.w * 0.125f);
  }

  const unsigned short* kb = kbf + (size_t)bh * Ss * Dd;
  const unsigned short* vb = vtbf + (size_t)bh * Dd * Ss;
  const int* mrowp = mask + (size_t)b * Ss;

  float m = -1e30f, l = 0.0f;

  // ---------------- pass 1: online max/sum (stats only) ----------------
  for (int j = 0; j <= qt; ++j) {
    unsigned long long mm = __ballot(mrowp[j * 64 + lane] != 0);
    float sv[16];
#pragma unroll
    for (int c = 0; c < 4; ++c) {
      const unsigned short* kr = kb + (size_t)(j * 64 + c * 16 + ln15) * Dd + quad * 8;
      bf16x8 kf0 = *(const bf16x8*)(kr);
      bf16x8 kf1 = *(const bf16x8*)(kr + 32);
      f32x4 acc = {0.f, 0.f, 0.f, 0.f};
      acc = __builtin_amdgcn_mfma_f32_16x16x32_bf16(kf0, qf0, acc, 0, 0, 0);
      acc = __builtin_amdgcn_mfma_f32_16x16x32_bf16(kf1, qf1, acc, 0, 0, 0);
#pragma unroll
      for (int r = 0; r < 4; ++r) sv[c * 4 + r] = acc[r];
    }
    if (j == qt || mm != ~0ull) {  // interior full-mask tiles skip this entirely
#pragma unroll
      for (int c = 0; c < 4; ++c)
#pragma unroll
        for (int r = 0; r < 4; ++r) {
          int kl = c * 16 + quad * 4 + r;
          bool mz = !((mm >> kl) & 1);
          if (j * 64 + kl > qg || mz) sv[c * 4 + r] = NEG;
        }
    }
    float t0 = fmaxf(fmaxf(sv[0], sv[1]), fmaxf(sv[2], sv[3]));
    float t1 = fmaxf(fmaxf(sv[4], sv[5]), fmaxf(sv[6], sv[7]));
    float t2 = fmaxf(fmaxf(sv[8], sv[9]), fmaxf(sv[10], sv[11]));
    float t3 = fmaxf(fmaxf(sv[12], sv[13]), fmaxf(sv[14], sv[15]));
    float tm = fmaxf(fmaxf(t0, t1), fmaxf(t2, t3));
    tm = fmaxf(tm, __shfl_xor(tm, 16));
    tm = fmaxf(tm, __shfl_xor(tm, 32));
    float mnew = fmaxf(m, tm);
    float ss = 0.f;
#pragma unroll
    for (int i = 0; i < 16; ++i) ss += __expf(sv[i] - mnew);
    ss += __shfl_xor(ss, 16);
    ss += __shfl_xor(ss, 32);
    l = l * __expf(m - mnew) + ss;
    m = mnew;
  }

  const float rl = 1.0f / l;
  f32x4 oacc[4];
#pragma unroll
  for (int c = 0; c < 4; ++c) oacc[c] = (f32x4){0.f, 0.f, 0.f, 0.f};

  float* arow = attn + ((size_t)bh * Ss + qg) * Ss;

  // ---------------- pass 2: recompute, write attn (float4), accumulate O ----------------
  for (int j = 0; j < 32; ++j) {
    if (j <= qt) {
      unsigned long long mm = __ballot(mrowp[j * 64 + lane] != 0);
      float sv[16];
#pragma unroll
      for (int c = 0; c < 4; ++c) {
        const unsigned short* kr = kb + (size_t)(j * 64 + c * 16 + ln15) * Dd + quad * 8;
        bf16x8 kf0 = *(const bf16x8*)(kr);
        bf16x8 kf1 = *(const bf16x8*)(kr + 32);
        f32x4 acc = {0.f, 0.f, 0.f, 0.f};
        acc = __builtin_amdgcn_mfma_f32_16x16x32_bf16(kf0, qf0, acc, 0, 0, 0);
        acc = __builtin_amdgcn_mfma_f32_16x16x32_bf16(kf1, qf1, acc, 0, 0, 0);
#pragma unroll
        for (int r = 0; r < 4; ++r) sv[c * 4 + r] = acc[r];
      }
      if (j == qt || mm != ~0ull) {
#pragma unroll
        for (int c = 0; c < 4; ++c)
#pragma unroll
          for (int r = 0; r < 4; ++r) {
            int kl = c * 16 + quad * 4 + r;
            bool mz = !((mm >> kl) & 1);
            if (j * 64 + kl > qg || mz) sv[c * 4 + r] = NEG;
          }
      }
#pragma unroll
      for (int c = 0; c < 4; ++c) {
        float4 pv;
        pv.x = __expf(sv[c * 4 + 0] - m) * rl;
        pv.y = __expf(sv[c * 4 + 1] - m) * rl;
        pv.z = __expf(sv[c * 4 + 2] - m) * rl;
        pv.w = __expf(sv[c * 4 + 3] - m) * rl;
        *(float4*)&arow[j * 64 + c * 16 + quad * 4] = pv;
        ushort4 u;
        u.x = f2bf(pv.x); u.y = f2bf(pv.y); u.z = f2bf(pv.z); u.w = f2bf(pv.w);
        *(ushort4*)&Plds[qloc * 72 + c * 16 + quad * 4] = u;  // own-wave strip only
      }
#pragma unroll
      for (int ch = 0; ch < 2; ++ch) {
        bf16x8 pf = *(const bf16x8*)&Plds[qloc * 72 + quad * 8 + 32 * ch];
#pragma unroll
        for (int c = 0; c < 4; ++c) {
          bf16x8 vf = *(const bf16x8*)&vb[(size_t)(c * 16 + ln15) * Ss + j * 64 + quad * 8 + 32 * ch];
          oacc[c] = __builtin_amdgcn_mfma_f32_16x16x32_bf16(vf, pf, oacc[c], 0, 0, 0);
        }
      }
    } else {
      // strictly above the diagonal: pure zero-fill, coalesced float4
      float4 z = {0.f, 0.f, 0.f, 0.f};
#pragma unroll
      for (int i = 0; i < 4; ++i) {
        int idx4 = tid + i * 256;
        int row = idx4 >> 4, col = (idx4 & 15) * 4;
        *(float4*)&attn[((size_t)bh * Ss + qt * 64 + row) * Ss + j * 64 + col] = z;
      }
    }
  }

  // ---- write O: float4 per c (d-contiguous in the swapped layout) ----
#pragma unroll
  for (int c = 0; c < 4; ++c)
    *(f32x4*)&out[((size_t)bh * Ss + qg) * Dd + c * 16 + quad * 4] = oacc[c];
}

// ---------------- fallback (proven kernel) if workspace is too small ----------------
__global__ __launch_bounds__(256) void attn_kernel_fb(
    const float* __restrict__ q, const float* __restrict__ k,
    const float* __restrict__ v, const int* __restrict__ mask,
    float* __restrict__ out, float* __restrict__ attn) {
  const int tid  = threadIdx.x;
  const int wave = tid >> 6;
  const int lane = tid & 63;
  const int quad = lane >> 4;
  const int ln15 = lane & 15;

  const int bh = blockIdx.x & 31;
  const int qt = 31 - (blockIdx.x >> 5);
  const int b  = bh >> 4;

  __shared__ unsigned short Klds[64 * 72];
  __shared__ unsigned short Vlds[64 * 72];
  __shared__ unsigned short Plds[64 * 72];

  {
    const float* qp = q + ((size_t)bh * Ss + (size_t)qt * 64) * Dd;
#pragma unroll
    for (int i = 0; i < 4; ++i) {
      int idx4 = tid + i * 256;
      int row = idx4 >> 4, col = (idx4 & 15) * 4;
      float4 f = *(const float4*)(qp + row * 64 + col);
      ushort4 u;
      u.x = f2bf(f.x * 0.125f); u.y = f2bf(f.y * 0.125f);
      u.z = f2bf(f.z * 0.125f); u.w = f2bf(f.w * 0.125f);
      *(ushort4*)&Vlds[row * 72 + col] = u;
    }
  }
  __syncthreads();
  const bf16x8 qfrag0 = *(const bf16x8*)&Vlds[(wave * 16 + ln15) * 72 + quad * 8];
  const bf16x8 qfrag1 = *(const bf16x8*)&Vlds[(wave * 16 + ln15) * 72 + quad * 8 + 32];

  float mrow[4], lrow[4];
#pragma unroll
  for (int r = 0; r < 4; ++r) { mrow[r] = -1e30f; lrow[r] = 0.0f; }

  for (int j = 0; j <= qt; ++j) {
    __syncthreads();
    {
      const float* kp = k + ((size_t)bh * Ss + (size_t)j * 64) * Dd;
#pragma unroll
      for (int i = 0; i < 4; ++i) {
        int idx4 = tid + i * 256;
        int row = idx4 >> 4, col = (idx4 & 15) * 4;
        float4 f = *(const float4*)(kp + row * 64 + col);
        ushort4 u;
        u.x = f2bf(f.x); u.y = f2bf(f.y); u.z = f2bf(f.z); u.w = f2bf(f.w);
        *(ushort4*)&Klds[row * 72 + col] = u;
      }
    }
    __syncthreads();
    unsigned long long mm = __ballot(mask[(size_t)b * Ss + j * 64 + lane] != 0);

    float sv[4][4];
#pragma unroll
    for (int c = 0; c < 4; ++c) {
      bf16x8 kf0 = *(const bf16x8*)&Klds[(c * 16 + ln15) * 72 + quad * 8];
      bf16x8 kf1 = *(const bf16x8*)&Klds[(c * 16 + ln15) * 72 + quad * 8 + 32];
      f32x4 acc = {0.f, 0.f, 0.f, 0.f};
      acc = __builtin_amdgcn_mfma_f32_16x16x32_bf16(qfrag0, kf0, acc, 0, 0, 0);
      acc = __builtin_amdgcn_mfma_f32_16x16x32_bf16(qfrag1, kf1, acc, 0, 0, 0);
      int col = j * 64 + c * 16 + ln15;
      bool mz = !((mm >> (c * 16 + ln15)) & 1);
#pragma unroll
      for (int r = 0; r < 4; ++r) {
        int row = qt * 64 + wave * 16 + quad * 4 + r;
        float val = acc[r];
        if (col > row || mz) val = NEG;
        sv[c][r] = val;
      }
    }
#pragma unroll
    for (int r = 0; r < 4; ++r) {
      float tm = fmaxf(fmaxf(sv[0][r], sv[1][r]), fmaxf(sv[2][r], sv[3][r]));
      tm = fmaxf(tm, __shfl_xor(tm, 1));
      tm = fmaxf(tm, __shfl_xor(tm, 2));
      tm = fmaxf(tm, __shfl_xor(tm, 4));
      tm = fmaxf(tm, __shfl_xor(tm, 8));
      float mnew = fmaxf(mrow[r], tm);
      float ss = __expf(sv[0][r] - mnew) + __expf(sv[1][r] - mnew) +
                 __expf(sv[2][r] - mnew) + __expf(sv[3][r] - mnew);
      ss += __shfl_xor(ss, 1);
      ss += __shfl_xor(ss, 2);
      ss += __shfl_xor(ss, 4);
      ss += __shfl_xor(ss, 8);
      lrow[r] = lrow[r] * __expf(mrow[r] - mnew) + ss;
      mrow[r] = mnew;
    }
  }

  float rl4[4];
#pragma unroll
  for (int r = 0; r < 4; ++r) rl4[r] = 1.0f / lrow[r];

  f32x4 oacc[4];
#pragma unroll
  for (int c = 0; c < 4; ++c) oacc[c] = (f32x4){0.f, 0.f, 0.f, 0.f};

  for (int j = 0; j < 32; ++j) {
    if (j <= qt) {
      __syncthreads();
      {
        const float* kp = k + ((size_t)bh * Ss + (size_t)j * 64) * Dd;
        const float* vp = v + ((size_t)bh * Ss + (size_t)j * 64) * Dd;
#pragma unroll
        for (int i = 0; i < 4; ++i) {
          int idx4 = tid + i * 256;
          int row = idx4 >> 4, col = (idx4 & 15) * 4;
          float4 f = *(const float4*)(kp + row * 64 + col);
          ushort4 u;
          u.x = f2bf(f.x); u.y = f2bf(f.y); u.z = f2bf(f.z); u.w = f2bf(f.w);
          *(ushort4*)&Klds[row * 72 + col] = u;
          float4 g = *(const float4*)(vp + row * 64 + col);
          ushort4 w2;
          w2.x = f2bf(g.x); w2.y = f2bf(g.y); w2.z = f2bf(g.z); w2.w = f2bf(g.w);
          *(ushort4*)&Vlds[row * 72 + col] = w2;
        }
      }
      __syncthreads();
      unsigned long long mm = __ballot(mask[(size_t)b * Ss + j * 64 + lane] != 0);
#pragma unroll
      for (int c = 0; c < 4; ++c) {
        bf16x8 kf0 = *(const bf16x8*)&Klds[(c * 16 + ln15) * 72 + quad * 8];
        bf16x8 kf1 = *(const bf16x8*)&Klds[(c * 16 + ln15) * 72 + quad * 8 + 32];
        f32x4 acc = {0.f, 0.f, 0.f, 0.f};
        acc = __builtin_amdgcn_mfma_f32_16x16x32_bf16(qfrag0, kf0, acc, 0, 0, 0);
        acc = __builtin_amdgcn_mfma_f32_16x16x32_bf16(qfrag1, kf1, acc, 0, 0, 0);
        int col = j * 64 + c * 16 + ln15;
        bool mz = !((mm >> (c * 16 + ln15)) & 1);
#pragma unroll
        for (int r = 0; r < 4; ++r) {
          int row = qt * 64 + wave * 16 + quad * 4 + r;
          float val = acc[r];
          if (col > row || mz) val = NEG;
          float p = __expf(val - mrow[r]) * rl4[r];
          attn[((size_t)bh * Ss + row) * Ss + col] = p;
          Plds[(wave * 16 + quad * 4 + r) * 72 + c * 16 + ln15] = f2bf(p);
        }
      }
#pragma unroll
      for (int ch = 0; ch < 2; ++ch) {
        bf16x8 pf = *(const bf16x8*)&Plds[(wave * 16 + ln15) * 72 + quad * 8 + 32 * ch];
#pragma unroll
        for (int c = 0; c < 4; ++c) {
          bf16x8 vf;
#pragma unroll
          for (int jj = 0; jj < 8; ++jj)
            vf[jj] = (short)Vlds[(quad * 8 + jj + 32 * ch) * 72 + c * 16 + ln15];
          oacc[c] = __builtin_amdgcn_mfma_f32_16x16x32_bf16(pf, vf, oacc[c], 0, 0, 0);
        }
      }
    } else {
      float4 z = {0.f, 0.f, 0.f, 0.f};
#pragma unroll
      for (int i = 0; i < 4; ++i) {
        int idx4 = tid + i * 256;
        int row = idx4 >> 4, col = (idx4 & 15) * 4;
        *(float4*)&attn[((size_t)bh * Ss + qt * 64 + row) * Ss + j * 64 + col] = z;
      }
    }
  }

#pragma unroll
  for (int c = 0; c < 4; ++c)
#pragma unroll
    for (int r = 0; r < 4; ++r) {
      int row = qt * 64 + wave * 16 + quad * 4 + r;
      out[((size_t)bh * Ss + row) * Dd + c * 16 + ln15] = oacc[c][r];
    }
}

extern "C" void kernel_launch(void* const* d_in, const int* in_sizes, int n_in,
                              void* d_out, int out_size, void* d_ws, size_t ws_size,
                              hipStream_t stream) {
  const float* q    = (const float*)d_in[0];
  const float* k    = (const float*)d_in[1];
  const float* v    = (const float*)d_in[2];
  const int*   mask = (const int*)d_in[3];
  float* out  = (float*)d_out;
  float* attn = out + (size_t)2 * 16 * 2048 * 64;  // out first, then attn

  const size_t need = (size_t)2 * 32 * Ss * Dd * sizeof(unsigned short);  // 16 MiB
  if (d_ws != nullptr && ws_size >= need) {
    unsigned short* kbf  = (unsigned short*)d_ws;
    unsigned short* vtbf = kbf + (size_t)32 * Ss * Dd;
    prep_kernel<<<dim3(32 * 32), dim3(256), 0, stream>>>(k, v, kbf, vtbf);
    attn_kernel<<<dim3(32 * 32), dim3(256), 0, stream>>>(q, kbf, vtbf, mask, out, attn);
  } else {
    attn_kernel_fb<<<dim3(32 * 32), dim3(256), 0, stream>>>(q, k, v, mask, out, attn);
  }
}

// Round 2
// 646.727 us; speedup vs baseline: 1.1895x; 1.1895x over previous
//
#include <hip/hip_runtime.h>

#define NEG (-1e9f)

typedef __attribute__((ext_vector_type(8))) short bf16x8;
typedef __attribute__((ext_vector_type(4))) float f32x4;

static constexpr int Ss = 2048, Dd = 64;

__device__ __forceinline__ unsigned short f2bf(float f) {
  union { float f; unsigned u; } v; v.f = f;
  unsigned r = v.u + 0x7FFF + ((v.u >> 16) & 1);  // RTNE
  return (unsigned short)(r >> 16);
}

// async global->LDS, 16B per lane; LDS dest = wave-uniform base + lane*16
__device__ __forceinline__ void gl_lds16(const unsigned short* g, unsigned short* l) {
  __builtin_amdgcn_global_load_lds(
      (const __attribute__((address_space(1))) unsigned int*)g,
      (__attribute__((address_space(3))) unsigned int*)l, 16, 0, 0);
}

// XOR-swizzled P tile [64 q-rows][64 k-cols] (ushort idx); flips bits 3..5 within row
#define PIDX(row, col) ((((row) * 64) + (col)) ^ (((row) & 7) << 3))

// ---------------- prep: K,V -> bf16 in MFMA-fragment order, tile-contiguous ----------------
// per (bh, tile j): 4096 ushorts K + 4096 ushorts V.
// K chunk (c,phase): lane (quad,ln15) holds K[j*64+c*16+ln15][quad*8+phase*32+i], i=0..7
// V chunk (c,ch):    lane (quad,ln15) holds V[j*64+ch*32+quad*8+i][c*16+ln15],    i=0..7
__global__ __launch_bounds__(256) void prep_kernel(
    const float* __restrict__ k, const float* __restrict__ v,
    unsigned short* __restrict__ kbf, unsigned short* __restrict__ vtbf) {
  const int tid = threadIdx.x;
  const int bh = blockIdx.x >> 5;
  const int j  = blockIdx.x & 31;
  __shared__ __align__(16) unsigned short Kl[64 * 72];
  __shared__ __align__(16) unsigned short Vl[64 * 72];
  const size_t base = ((size_t)bh * Ss + (size_t)j * 64) * Dd;
#pragma unroll
  for (int i = 0; i < 4; ++i) {
    int idx4 = tid + i * 256;
    int row = idx4 >> 4, col = (idx4 & 15) * 4;
    float4 f = *(const float4*)(k + base + row * 64 + col);
    ushort4 u;
    u.x = f2bf(f.x); u.y = f2bf(f.y); u.z = f2bf(f.z); u.w = f2bf(f.w);
    *(ushort4*)&Kl[row * 72 + col] = u;
    float4 g = *(const float4*)(v + base + row * 64 + col);
    ushort4 w;
    w.x = f2bf(g.x); w.y = f2bf(g.y); w.z = f2bf(g.z); w.w = f2bf(g.w);
    *(ushort4*)&Vl[row * 72 + col] = w;
  }
  __syncthreads();
  const size_t tb = ((size_t)bh * 32 + j) * 4096;
#pragma unroll
  for (int t = 0; t < 2; ++t) {
    int id = tid + t * 256;
    int ck = id >> 6, ln = id & 63;
    int c = ck >> 1, ph = ck & 1;
    bf16x8 val = *(const bf16x8*)&Kl[(c * 16 + (ln & 15)) * 72 + (ln >> 4) * 8 + ph * 32];
    *(bf16x8*)&kbf[tb + ck * 512 + ln * 8] = val;
  }
#pragma unroll
  for (int t = 0; t < 2; ++t) {
    int id = tid + t * 256;
    int ck = id >> 6, ln = id & 63;
    int c = ck >> 1, ch = ck & 1;
    bf16x8 val;
#pragma unroll
    for (int i = 0; i < 8; ++i)
      val[i] = (short)Vl[(ch * 32 + (ln >> 4) * 8 + i) * 72 + c * 16 + (ln & 15)];
    *(bf16x8*)&vtbf[tb + ck * 512 + ln * 8] = val;
  }
}

// ---------------- main: swapped MFMA, LDS dbuf staging via global_load_lds ----------------
__global__ __launch_bounds__(256) void attn_kernel(
    const float* __restrict__ q, const unsigned short* __restrict__ kbf,
    const unsigned short* __restrict__ vtbf, const int* __restrict__ mask,
    float* __restrict__ out, float* __restrict__ attn) {
  const int tid = threadIdx.x;
  const int wave = tid >> 6, lane = tid & 63, quad = lane >> 4, ln15 = lane & 15;
  const int bh = blockIdx.x & 31;          // same bh -> same XCD (stride 32 ≡ 0 mod 8)
  // balanced qt mapping: per stride-256 block group, per-CU work sums are equal
  const int g = blockIdx.x >> 5, h = g & 7, kk = g >> 3;
  const int qt = (kk < 2) ? (h * 2 + kk) : (31 - h * 2 - (kk & 1));
  const int b = bh >> 4;                   // H = 16
  const int qloc = wave * 16 + ln15;
  const int qg = qt * 64 + qloc;

  __shared__ __align__(16) unsigned short Kb[2 * 4096];  // 16 KB dbuf
  __shared__ __align__(16) unsigned short Vb[2 * 4096];  // 16 KB dbuf
  __shared__ __align__(16) unsigned short Plds[4096];    // 8 KB swizzled

  // Q fragments (B-operand: lane ln15 = q row, quad*8+i = d), scaled by 1/8 exact
  bf16x8 qf0, qf1;
  {
    const float* qp = q + ((size_t)bh * Ss + qg) * Dd + quad * 8;
    float4 f0 = *(const float4*)(qp);
    float4 f1 = *(const float4*)(qp + 4);
    float4 f2 = *(const float4*)(qp + 32);
    float4 f3 = *(const float4*)(qp + 36);
    qf0[0] = (short)f2bf(f0.x * 0.125f); qf0[1] = (short)f2bf(f0.y * 0.125f);
    qf0[2] = (short)f2bf(f0.z * 0.125f); qf0[3] = (short)f2bf(f0.w * 0.125f);
    qf0[4] = (short)f2bf(f1.x * 0.125f); qf0[5] = (short)f2bf(f1.y * 0.125f);
    qf0[6] = (short)f2bf(f1.z * 0.125f); qf0[7] = (short)f2bf(f1.w * 0.125f);
    qf1[0] = (short)f2bf(f2.x * 0.125f); qf1[1] = (short)f2bf(f2.y * 0.125f);
    qf1[2] = (short)f2bf(f2.z * 0.125f); qf1[3] = (short)f2bf(f2.w * 0.125f);
    qf1[4] = (short)f2bf(f3.x * 0.125f); qf1[5] = (short)f2bf(f3.y * 0.125f);
    qf1[6] = (short)f2bf(f3.z * 0.125f); qf1[7] = (short)f2bf(f3.w * 0.125f);
  }

  const unsigned short* kt = kbf + ((size_t)bh * 32) * 4096;
  const unsigned short* vt = vtbf + ((size_t)bh * 32) * 4096;
  const int* mrowp = mask + (size_t)b * Ss;
  const int c0 = wave * 2, c1 = wave * 2 + 1;

  float m = -1e30f, l = 0.0f;

  // ---------------- pass 1: online max/sum (K only) ----------------
  gl_lds16(kt + c0 * 512 + lane * 8, &Kb[c0 * 512]);
  gl_lds16(kt + c1 * 512 + lane * 8, &Kb[c1 * 512]);
  __syncthreads();
  for (int j = 0; j <= qt; ++j) {
    const int cur = j & 1;
    if (j < qt) {  // stage next tile into other buffer; drained at end-of-iter barrier
      const unsigned short* nt = kt + (size_t)(j + 1) * 4096;
      gl_lds16(nt + c0 * 512 + lane * 8, &Kb[(cur ^ 1) * 4096 + c0 * 512]);
      gl_lds16(nt + c1 * 512 + lane * 8, &Kb[(cur ^ 1) * 4096 + c1 * 512]);
    }
    unsigned long long mm = __ballot(mrowp[j * 64 + lane] != 0);
    float sv[16];
#pragma unroll
    for (int c = 0; c < 4; ++c) {
      bf16x8 kf0 = *(const bf16x8*)&Kb[cur * 4096 + (c * 2 + 0) * 512 + lane * 8];
      bf16x8 kf1 = *(const bf16x8*)&Kb[cur * 4096 + (c * 2 + 1) * 512 + lane * 8];
      f32x4 acc = {0.f, 0.f, 0.f, 0.f};
      acc = __builtin_amdgcn_mfma_f32_16x16x32_bf16(kf0, qf0, acc, 0, 0, 0);
      acc = __builtin_amdgcn_mfma_f32_16x16x32_bf16(kf1, qf1, acc, 0, 0, 0);
#pragma unroll
      for (int r = 0; r < 4; ++r) sv[c * 4 + r] = acc[r];
    }
    if (j == qt || mm != ~0ull) {  // interior full-mask tiles skip masking
#pragma unroll
      for (int c = 0; c < 4; ++c)
#pragma unroll
        for (int r = 0; r < 4; ++r) {
          int kl = c * 16 + quad * 4 + r;
          bool mz = !((mm >> kl) & 1);
          if (j * 64 + kl > qg || mz) sv[c * 4 + r] = NEG;
        }
    }
    float t0 = fmaxf(fmaxf(sv[0], sv[1]), fmaxf(sv[2], sv[3]));
    float t1 = fmaxf(fmaxf(sv[4], sv[5]), fmaxf(sv[6], sv[7]));
    float t2 = fmaxf(fmaxf(sv[8], sv[9]), fmaxf(sv[10], sv[11]));
    float t3 = fmaxf(fmaxf(sv[12], sv[13]), fmaxf(sv[14], sv[15]));
    float tm = fmaxf(fmaxf(t0, t1), fmaxf(t2, t3));
    tm = fmaxf(tm, __shfl_xor(tm, 16));
    tm = fmaxf(tm, __shfl_xor(tm, 32));
    float mnew = fmaxf(m, tm);
    float ss = 0.f;
#pragma unroll
    for (int i = 0; i < 16; ++i) ss += __expf(sv[i] - mnew);
    ss += __shfl_xor(ss, 16);
    ss += __shfl_xor(ss, 32);
    l = l * __expf(m - mnew) + ss;
    m = mnew;
    __syncthreads();
  }

  const float rl = 1.0f / l;
  f32x4 oacc[4];
#pragma unroll
  for (int c = 0; c < 4; ++c) oacc[c] = (f32x4){0.f, 0.f, 0.f, 0.f};
  float* arow = attn + ((size_t)bh * Ss + qg) * Ss;

  // ---------------- pass 2: recompute, write attn, O = P·V ----------------
  gl_lds16(kt + c0 * 512 + lane * 8, &Kb[c0 * 512]);
  gl_lds16(kt + c1 * 512 + lane * 8, &Kb[c1 * 512]);
  gl_lds16(vt + c0 * 512 + lane * 8, &Vb[c0 * 512]);
  gl_lds16(vt + c1 * 512 + lane * 8, &Vb[c1 * 512]);
  __syncthreads();
  for (int j = 0; j <= qt; ++j) {
    const int cur = j & 1;
    if (j < qt) {
      const unsigned short* ntk = kt + (size_t)(j + 1) * 4096;
      const unsigned short* ntv = vt + (size_t)(j + 1) * 4096;
      gl_lds16(ntk + c0 * 512 + lane * 8, &Kb[(cur ^ 1) * 4096 + c0 * 512]);
      gl_lds16(ntk + c1 * 512 + lane * 8, &Kb[(cur ^ 1) * 4096 + c1 * 512]);
      gl_lds16(ntv + c0 * 512 + lane * 8, &Vb[(cur ^ 1) * 4096 + c0 * 512]);
      gl_lds16(ntv + c1 * 512 + lane * 8, &Vb[(cur ^ 1) * 4096 + c1 * 512]);
    }
    unsigned long long mm = __ballot(mrowp[j * 64 + lane] != 0);
    float sv[16];
#pragma unroll
    for (int c = 0; c < 4; ++c) {
      bf16x8 kf0 = *(const bf16x8*)&Kb[cur * 4096 + (c * 2 + 0) * 512 + lane * 8];
      bf16x8 kf1 = *(const bf16x8*)&Kb[cur * 4096 + (c * 2 + 1) * 512 + lane * 8];
      f32x4 acc = {0.f, 0.f, 0.f, 0.f};
      acc = __builtin_amdgcn_mfma_f32_16x16x32_bf16(kf0, qf0, acc, 0, 0, 0);
      acc = __builtin_amdgcn_mfma_f32_16x16x32_bf16(kf1, qf1, acc, 0, 0, 0);
#pragma unroll
      for (int r = 0; r < 4; ++r) sv[c * 4 + r] = acc[r];
    }
    if (j == qt || mm != ~0ull) {
#pragma unroll
      for (int c = 0; c < 4; ++c)
#pragma unroll
        for (int r = 0; r < 4; ++r) {
          int kl = c * 16 + quad * 4 + r;
          bool mz = !((mm >> kl) & 1);
          if (j * 64 + kl > qg || mz) sv[c * 4 + r] = NEG;
        }
    }
#pragma unroll
    for (int c = 0; c < 4; ++c) {
      float4 pv;
      pv.x = __expf(sv[c * 4 + 0] - m) * rl;
      pv.y = __expf(sv[c * 4 + 1] - m) * rl;
      pv.z = __expf(sv[c * 4 + 2] - m) * rl;
      pv.w = __expf(sv[c * 4 + 3] - m) * rl;
      *(float4*)&arow[j * 64 + c * 16 + quad * 4] = pv;
      ushort4 u;
      u.x = f2bf(pv.x); u.y = f2bf(pv.y); u.z = f2bf(pv.z); u.w = f2bf(pv.w);
      *(ushort4*)&Plds[PIDX(qloc, c * 16 + quad * 4)] = u;  // own-wave strip only
    }
#pragma unroll
    for (int ch = 0; ch < 2; ++ch) {
      bf16x8 pf = *(const bf16x8*)&Plds[PIDX(qloc, quad * 8 + 32 * ch)];
#pragma unroll
      for (int c = 0; c < 4; ++c) {
        bf16x8 vf = *(const bf16x8*)&Vb[cur * 4096 + (c * 2 + ch) * 512 + lane * 8];
        oacc[c] = __builtin_amdgcn_mfma_f32_16x16x32_bf16(vf, pf, oacc[c], 0, 0, 0);
      }
    }
    __syncthreads();
  }

  // zero-fill strictly-above-diagonal tiles, coalesced float4
  for (int j = qt + 1; j < 32; ++j) {
    float4 z = {0.f, 0.f, 0.f, 0.f};
#pragma unroll
    for (int i = 0; i < 4; ++i) {
      int idx4 = tid + i * 256;
      int row = idx4 >> 4, col = (idx4 & 15) * 4;
      *(float4*)&attn[((size_t)bh * Ss + qt * 64 + row) * Ss + j * 64 + col] = z;
    }
  }

  // ---- write O: float4 per c ----
#pragma unroll
  for (int c = 0; c < 4; ++c)
    *(f32x4*)&out[((size_t)bh * Ss + qg) * Dd + c * 16 + quad * 4] = oacc[c];
}

// ---------------- fallback (proven 343us kernel) if workspace too small ----------------
__global__ __launch_bounds__(256) void attn_kernel_fb(
    const float* __restrict__ q, const float* __restrict__ k,
    const float* __restrict__ v, const int* __restrict__ mask,
    float* __restrict__ out, float* __restrict__ attn) {
  const int tid  = threadIdx.x;
  const int wave = tid >> 6;
  const int lane = tid & 63;
  const int quad = lane >> 4;
  const int ln15 = lane & 15;

  const int bh = blockIdx.x & 31;
  const int qt = 31 - (blockIdx.x >> 5);
  const int b  = bh >> 4;

  __shared__ unsigned short Klds[64 * 72];
  __shared__ unsigned short Vlds[64 * 72];
  __shared__ unsigned short Plds2[64 * 72];

  {
    const float* qp = q + ((size_t)bh * Ss + (size_t)qt * 64) * Dd;
#pragma unroll
    for (int i = 0; i < 4; ++i) {
      int idx4 = tid + i * 256;
      int row = idx4 >> 4, col = (idx4 & 15) * 4;
      float4 f = *(const float4*)(qp + row * 64 + col);
      ushort4 u;
      u.x = f2bf(f.x * 0.125f); u.y = f2bf(f.y * 0.125f);
      u.z = f2bf(f.z * 0.125f); u.w = f2bf(f.w * 0.125f);
      *(ushort4*)&Vlds[row * 72 + col] = u;
    }
  }
  __syncthreads();
  const bf16x8 qfrag0 = *(const bf16x8*)&Vlds[(wave * 16 + ln15) * 72 + quad * 8];
  const bf16x8 qfrag1 = *(const bf16x8*)&Vlds[(wave * 16 + ln15) * 72 + quad * 8 + 32];

  float mrow[4], lrow[4];
#pragma unroll
  for (int r = 0; r < 4; ++r) { mrow[r] = -1e30f; lrow[r] = 0.0f; }

  for (int j = 0; j <= qt; ++j) {
    __syncthreads();
    {
      const float* kp = k + ((size_t)bh * Ss + (size_t)j * 64) * Dd;
#pragma unroll
      for (int i = 0; i < 4; ++i) {
        int idx4 = tid + i * 256;
        int row = idx4 >> 4, col = (idx4 & 15) * 4;
        float4 f = *(const float4*)(kp + row * 64 + col);
        ushort4 u;
        u.x = f2bf(f.x); u.y = f2bf(f.y); u.z = f2bf(f.z); u.w = f2bf(f.w);
        *(ushort4*)&Klds[row * 72 + col] = u;
      }
    }
    __syncthreads();
    unsigned long long mm = __ballot(mask[(size_t)b * Ss + j * 64 + lane] != 0);

    float sv[4][4];
#pragma unroll
    for (int c = 0; c < 4; ++c) {
      bf16x8 kf0 = *(const bf16x8*)&Klds[(c * 16 + ln15) * 72 + quad * 8];
      bf16x8 kf1 = *(const bf16x8*)&Klds[(c * 16 + ln15) * 72 + quad * 8 + 32];
      f32x4 acc = {0.f, 0.f, 0.f, 0.f};
      acc = __builtin_amdgcn_mfma_f32_16x16x32_bf16(qfrag0, kf0, acc, 0, 0, 0);
      acc = __builtin_amdgcn_mfma_f32_16x16x32_bf16(qfrag1, kf1, acc, 0, 0, 0);
      int col = j * 64 + c * 16 + ln15;
      bool mz = !((mm >> (c * 16 + ln15)) & 1);
#pragma unroll
      for (int r = 0; r < 4; ++r) {
        int row = qt * 64 + wave * 16 + quad * 4 + r;
        float val = acc[r];
        if (col > row || mz) val = NEG;
        sv[c][r] = val;
      }
    }
#pragma unroll
    for (int r = 0; r < 4; ++r) {
      float tm = fmaxf(fmaxf(sv[0][r], sv[1][r]), fmaxf(sv[2][r], sv[3][r]));
      tm = fmaxf(tm, __shfl_xor(tm, 1));
      tm = fmaxf(tm, __shfl_xor(tm, 2));
      tm = fmaxf(tm, __shfl_xor(tm, 4));
      tm = fmaxf(tm, __shfl_xor(tm, 8));
      float mnew = fmaxf(mrow[r], tm);
      float ss = __expf(sv[0][r] - mnew) + __expf(sv[1][r] - mnew) +
                 __expf(sv[2][r] - mnew) + __expf(sv[3][r] - mnew);
      ss += __shfl_xor(ss, 1);
      ss += __shfl_xor(ss, 2);
      ss += __shfl_xor(ss, 4);
      ss += __shfl_xor(ss, 8);
      lrow[r] = lrow[r] * __expf(mrow[r] - mnew) + ss;
      mrow[r] = mnew;
    }
  }

  float rl4[4];
#pragma unroll
  for (int r = 0; r < 4; ++r) rl4[r] = 1.0f / lrow[r];

  f32x4 oacc[4];
#pragma unroll
  for (int c = 0; c < 4; ++c) oacc[c] = (f32x4){0.f, 0.f, 0.f, 0.f};

  for (int j = 0; j < 32; ++j) {
    if (j <= qt) {
      __syncthreads();
      {
        const float* kp = k + ((size_t)bh * Ss + (size_t)j * 64) * Dd;
        const float* vp = v + ((size_t)bh * Ss + (size_t)j * 64) * Dd;
#pragma unroll
        for (int i = 0; i < 4; ++i) {
          int idx4 = tid + i * 256;
          int row = idx4 >> 4, col = (idx4 & 15) * 4;
          float4 f = *(const float4*)(kp + row * 64 + col);
          ushort4 u;
          u.x = f2bf(f.x); u.y = f2bf(f.y); u.z = f2bf(f.z); u.w = f2bf(f.w);
          *(ushort4*)&Klds[row * 72 + col] = u;
          float4 g = *(const float4*)(vp + row * 64 + col);
          ushort4 w2;
          w2.x = f2bf(g.x); w2.y = f2bf(g.y); w2.z = f2bf(g.z); w2.w = f2bf(g.w);
          *(ushort4*)&Vlds[row * 72 + col] = w2;
        }
      }
      __syncthreads();
      unsigned long long mm = __ballot(mask[(size_t)b * Ss + j * 64 + lane] != 0);
#pragma unroll
      for (int c = 0; c < 4; ++c) {
        bf16x8 kf0 = *(const bf16x8*)&Klds[(c * 16 + ln15) * 72 + quad * 8];
        bf16x8 kf1 = *(const bf16x8*)&Klds[(c * 16 + ln15) * 72 + quad * 8 + 32];
        f32x4 acc = {0.f, 0.f, 0.f, 0.f};
        acc = __builtin_amdgcn_mfma_f32_16x16x32_bf16(qfrag0, kf0, acc, 0, 0, 0);
        acc = __builtin_amdgcn_mfma_f32_16x16x32_bf16(qfrag1, kf1, acc, 0, 0, 0);
        int col = j * 64 + c * 16 + ln15;
        bool mz = !((mm >> (c * 16 + ln15)) & 1);
#pragma unroll
        for (int r = 0; r < 4; ++r) {
          int row = qt * 64 + wave * 16 + quad * 4 + r;
          float val = acc[r];
          if (col > row || mz) val = NEG;
          float p = __expf(val - mrow[r]) * rl4[r];
          attn[((size_t)bh * Ss + row) * Ss + col] = p;
          Plds2[(wave * 16 + quad * 4 + r) * 72 + c * 16 + ln15] = f2bf(p);
        }
      }
#pragma unroll
      for (int ch = 0; ch < 2; ++ch) {
        bf16x8 pf = *(const bf16x8*)&Plds2[(wave * 16 + ln15) * 72 + quad * 8 + 32 * ch];
#pragma unroll
        for (int c = 0; c < 4; ++c) {
          bf16x8 vf;
#pragma unroll
          for (int jj = 0; jj < 8; ++jj)
            vf[jj] = (short)Vlds[(quad * 8 + jj + 32 * ch) * 72 + c * 16 + ln15];
          oacc[c] = __builtin_amdgcn_mfma_f32_16x16x32_bf16(pf, vf, oacc[c], 0, 0, 0);
        }
      }
    } else {
      float4 z = {0.f, 0.f, 0.f, 0.f};
#pragma unroll
      for (int i = 0; i < 4; ++i) {
        int idx4 = tid + i * 256;
        int row = idx4 >> 4, col = (idx4 & 15) * 4;
        *(float4*)&attn[((size_t)bh * Ss + qt * 64 + row) * Ss + j * 64 + col] = z;
      }
    }
  }

#pragma unroll
  for (int c = 0; c < 4; ++c)
#pragma unroll
    for (int r = 0; r < 4; ++r) {
      int row = qt * 64 + wave * 16 + quad * 4 + r;
      out[((size_t)bh * Ss + row) * Dd + c * 16 + ln15] = oacc[c][r];
    }
}

extern "C" void kernel_launch(void* const* d_in, const int* in_sizes, int n_in,
                              void* d_out, int out_size, void* d_ws, size_t ws_size,
                              hipStream_t stream) {
  const float* q    = (const float*)d_in[0];
  const float* k    = (const float*)d_in[1];
  const float* v    = (const float*)d_in[2];
  const int*   mask = (const int*)d_in[3];
  float* out  = (float*)d_out;
  float* attn = out + (size_t)2 * 16 * 2048 * 64;  // out first, then attn

  const size_t need = (size_t)2 * 32 * Ss * Dd * sizeof(unsigned short);  // 16 MiB
  if (d_ws != nullptr && ws_size >= need) {
    unsigned short* kbf  = (unsigned short*)d_ws;
    unsigned short* vtbf = kbf + (size_t)32 * Ss * Dd;
    prep_kernel<<<dim3(32 * 32), dim3(256), 0, stream>>>(k, v, kbf, vtbf);
    attn_kernel<<<dim3(32 * 32), dim3(256), 0, stream>>>(q, kbf, vtbf, mask, out, attn);
  } else {
    attn_kernel_fb<<<dim3(32 * 32), dim3(256), 0, stream>>>(q, k, v, mask, out, attn);
  }
}

// Round 3
// 633.270 us; speedup vs baseline: 1.2147x; 1.0213x over previous
//
#include <hip/hip_runtime.h>

#define NEG (-1e9f)

typedef __attribute__((ext_vector_type(8))) short bf16x8;
typedef __attribute__((ext_vector_type(4))) float f32x4;

static constexpr int Ss = 2048, Dd = 64;

__device__ __forceinline__ unsigned short f2bf(float f) {
  union { float f; unsigned u; } v; v.f = f;
  unsigned r = v.u + 0x7FFF + ((v.u >> 16) & 1);  // RTNE
  return (unsigned short)(r >> 16);
}

// async global->LDS, 16B per lane; LDS dest = wave-uniform base + lane*16
__device__ __forceinline__ void gl_lds16(const unsigned short* g, unsigned short* l) {
  __builtin_amdgcn_global_load_lds(
      (const __attribute__((address_space(1))) unsigned int*)g,
      (__attribute__((address_space(3))) unsigned int*)l, 16, 0, 0);
}

// XOR-swizzled P tile [64 q-rows][64 k-cols] (ushort idx)
#define PIDX(row, col) ((((row) * 64) + (col)) ^ (((row) & 7) << 3))

// ---------------- init: zero flags/M ----------------
__global__ void init_kernel(unsigned* flagsM) {
  if (threadIdx.x < 64) flagsM[threadIdx.x] = 0;
}

// ---------------- prep: K,V -> bf16 fragment order; K norms; mask flag ----------------
__global__ __launch_bounds__(256) void prep_kernel(
    const float* __restrict__ k, const float* __restrict__ v,
    const int* __restrict__ mask,
    unsigned short* __restrict__ kbf, unsigned short* __restrict__ vtbf,
    unsigned* __restrict__ flagsM) {
  const int tid = threadIdx.x;
  const int bh = blockIdx.x >> 5;
  const int j  = blockIdx.x & 31;
  const int b  = bh >> 4;  // H = 16
  __shared__ __align__(16) unsigned short Kl[64 * 72];
  __shared__ __align__(16) unsigned short Vl[64 * 72];
  __shared__ float pn[64][16];
  const size_t base = ((size_t)bh * Ss + (size_t)j * 64) * Dd;
#pragma unroll
  for (int i = 0; i < 4; ++i) {
    int idx4 = tid + i * 256;
    int row = idx4 >> 4, col = (idx4 & 15) * 4;
    float4 f = *(const float4*)(k + base + row * 64 + col);
    ushort4 u;
    u.x = f2bf(f.x); u.y = f2bf(f.y); u.z = f2bf(f.z); u.w = f2bf(f.w);
    *(ushort4*)&Kl[row * 72 + col] = u;
    pn[row][idx4 & 15] = f.x * f.x + f.y * f.y + f.z * f.z + f.w * f.w;
    float4 g = *(const float4*)(v + base + row * 64 + col);
    ushort4 w;
    w.x = f2bf(g.x); w.y = f2bf(g.y); w.z = f2bf(g.z); w.w = f2bf(g.w);
    *(ushort4*)&Vl[row * 72 + col] = w;
  }
  __syncthreads();
  const size_t tb = ((size_t)bh * 32 + j) * 4096;
#pragma unroll
  for (int t = 0; t < 2; ++t) {
    int id = tid + t * 256;
    int ck = id >> 6, ln = id & 63;
    int c = ck >> 1, ph = ck & 1;
    bf16x8 val = *(const bf16x8*)&Kl[(c * 16 + (ln & 15)) * 72 + (ln >> 4) * 8 + ph * 32];
    *(bf16x8*)&kbf[tb + ck * 512 + ln * 8] = val;
  }
#pragma unroll
  for (int t = 0; t < 2; ++t) {
    int id = tid + t * 256;
    int ck = id >> 6, ln = id & 63;
    int c = ck >> 1, ch = ck & 1;
    bf16x8 val;
#pragma unroll
    for (int i = 0; i < 8; ++i)
      val[i] = (short)Vl[(ch * 32 + (ln >> 4) * 8 + i) * 72 + c * 16 + (ln & 15)];
    *(bf16x8*)&vtbf[tb + ck * 512 + ln * 8] = val;
  }
  // wave 0: max row-norm^2 of this K tile -> atomicMax; wave 1: mask-any-zero flag
  if (tid < 64) {
    const float4* pr = (const float4*)pn[tid];
    float4 a = pr[0], bq = pr[1], cq = pr[2], dq = pr[3];
    float s = a.x + a.y + a.z + a.w + bq.x + bq.y + bq.z + bq.w +
              cq.x + cq.y + cq.z + cq.w + dq.x + dq.y + dq.z + dq.w;
#pragma unroll
    for (int x = 1; x <= 32; x <<= 1) s = fmaxf(s, __shfl_xor(s, x));
    if (tid == 0) atomicMax(&flagsM[1 + bh], __float_as_uint(s));
  } else if (tid < 128) {
    int lane = tid - 64;
    unsigned long long mm = __ballot(mask[(size_t)b * Ss + j * 64 + lane] == 0);
    if (lane == 0 && mm != 0ull) atomicOr(&flagsM[0], 1u);
  }
}

// ---------------- main fast path: full mask; fixed-C softmax; counted vmcnt ----------------
__global__ __launch_bounds__(256) void attn_fast(
    const float* __restrict__ q, const unsigned short* __restrict__ kbf,
    const unsigned short* __restrict__ vtbf, const unsigned* __restrict__ flagsM,
    float* __restrict__ out, float* __restrict__ attn) {
  if (flagsM[0] != 0) return;  // mask has zeros -> fallback kernel handles
  const int tid = threadIdx.x;
  const int wave = tid >> 6, lane = tid & 63, quad = lane >> 4, ln15 = lane & 15;
  const int bh = blockIdx.x & 31;          // same bh -> same XCD
  const int g = blockIdx.x >> 5, h = g & 7, kk2 = g >> 3;
  const int qt = (kk2 < 2) ? (h * 2 + kk2) : (31 - h * 2 - (kk2 & 1));  // balanced
  const int qloc = wave * 16 + ln15;
  const int qg = qt * 64 + qloc;

  __shared__ __align__(16) unsigned short S4[4 * 4096];  // 32 KB: p1 ring / p2 dbuf
  __shared__ __align__(16) unsigned short Plds[4096];    // 8 KB swizzled

  // Q fragments (B-operand) scaled by 1/8 exact + row norm^2 of scaled q
  bf16x8 qf0, qf1;
  float qn2;
  {
    const float* qp = q + ((size_t)bh * Ss + qg) * Dd + quad * 8;
    float4 f0 = *(const float4*)(qp);
    float4 f1 = *(const float4*)(qp + 4);
    float4 f2 = *(const float4*)(qp + 32);
    float4 f3 = *(const float4*)(qp + 36);
    float s0 = f0.x * 0.125f, s1 = f0.y * 0.125f, s2 = f0.z * 0.125f, s3 = f0.w * 0.125f;
    float s4 = f1.x * 0.125f, s5 = f1.y * 0.125f, s6 = f1.z * 0.125f, s7 = f1.w * 0.125f;
    float t0 = f2.x * 0.125f, t1 = f2.y * 0.125f, t2 = f2.z * 0.125f, t3 = f2.w * 0.125f;
    float t4 = f3.x * 0.125f, t5 = f3.y * 0.125f, t6 = f3.z * 0.125f, t7 = f3.w * 0.125f;
    qf0[0] = (short)f2bf(s0); qf0[1] = (short)f2bf(s1); qf0[2] = (short)f2bf(s2); qf0[3] = (short)f2bf(s3);
    qf0[4] = (short)f2bf(s4); qf0[5] = (short)f2bf(s5); qf0[6] = (short)f2bf(s6); qf0[7] = (short)f2bf(s7);
    qf1[0] = (short)f2bf(t0); qf1[1] = (short)f2bf(t1); qf1[2] = (short)f2bf(t2); qf1[3] = (short)f2bf(t3);
    qf1[4] = (short)f2bf(t4); qf1[5] = (short)f2bf(t5); qf1[6] = (short)f2bf(t6); qf1[7] = (short)f2bf(t7);
    qn2 = s0*s0 + s1*s1 + s2*s2 + s3*s3 + s4*s4 + s5*s5 + s6*s6 + s7*s7 +
          t0*t0 + t1*t1 + t2*t2 + t3*t3 + t4*t4 + t5*t5 + t6*t6 + t7*t7;
    qn2 += __shfl_xor(qn2, 16);
    qn2 += __shfl_xor(qn2, 32);
  }
  const float Mn2 = __uint_as_float(flagsM[1 + bh]);
  const float C = sqrtf(qn2 * Mn2);  // >= row max score (Cauchy-Schwarz)

  const unsigned short* kt = kbf + ((size_t)bh * 32) * 4096;
  const unsigned short* vt = vtbf + ((size_t)bh * 32) * 4096;
  const int c0 = wave * 2, c1 = c0 + 1;

  asm volatile("s_waitcnt vmcnt(0)" ::: "memory");  // clean vmem state before counting

  // ---------------- pass 1: l = sum exp(s - C); 4-slot K ring, depth-3 ----------------
#pragma unroll
  for (int t = 0; t < 3; ++t) {
    const unsigned short* src = kt + (size_t)((t <= qt) ? t : qt) * 4096;
    gl_lds16(src + c0 * 512 + lane * 8, &S4[t * 4096 + c0 * 512]);
    gl_lds16(src + c1 * 512 + lane * 8, &S4[t * 4096 + c1 * 512]);
  }
  float l0 = 0.f, l1 = 0.f, l2 = 0.f, l3 = 0.f;
  for (int j = 0; j <= qt; ++j) {
    asm volatile("s_waitcnt vmcnt(4)" ::: "memory");  // my 2 loads for tile j landed
    __builtin_amdgcn_s_barrier();                     // everyone's landed; slot j-1 free
    asm volatile("" ::: "memory");
    {
      int nt = (j + 3 <= qt) ? (j + 3) : qt;          // dummy re-stage keeps count fixed
      const unsigned short* src = kt + (size_t)nt * 4096;
      unsigned short* dst = &S4[((j + 3) & 3) * 4096];
      gl_lds16(src + c0 * 512 + lane * 8, dst + c0 * 512);
      gl_lds16(src + c1 * 512 + lane * 8, dst + c1 * 512);
    }
    asm volatile("" ::: "memory");
    const unsigned short* sl = &S4[(j & 3) * 4096];
    float sv[16];
#pragma unroll
    for (int c = 0; c < 4; ++c) {
      bf16x8 kf0 = *(const bf16x8*)&sl[(c * 2 + 0) * 512 + lane * 8];
      bf16x8 kf1 = *(const bf16x8*)&sl[(c * 2 + 1) * 512 + lane * 8];
      f32x4 acc = {0.f, 0.f, 0.f, 0.f};
      acc = __builtin_amdgcn_mfma_f32_16x16x32_bf16(kf0, qf0, acc, 0, 0, 0);
      acc = __builtin_amdgcn_mfma_f32_16x16x32_bf16(kf1, qf1, acc, 0, 0, 0);
#pragma unroll
      for (int r = 0; r < 4; ++r) sv[c * 4 + r] = acc[r];
    }
    if (j == qt) {  // causal mask on diagonal tile only (mask is all-ones here)
#pragma unroll
      for (int c = 0; c < 4; ++c)
#pragma unroll
        for (int r = 0; r < 4; ++r)
          if (c * 16 + quad * 4 + r > qloc) sv[c * 4 + r] = NEG;
    }
#pragma unroll
    for (int i = 0; i < 16; i += 4) {
      l0 += __expf(sv[i + 0] - C);
      l1 += __expf(sv[i + 1] - C);
      l2 += __expf(sv[i + 2] - C);
      l3 += __expf(sv[i + 3] - C);
    }
  }
  float l = (l0 + l1) + (l2 + l3);
  l += __shfl_xor(l, 16);
  l += __shfl_xor(l, 32);
  const float msum = C + __logf(l);  // p = exp(s - msum), already normalized

  __syncthreads();  // pass boundary: drain ring loads, re-sync all waves

  // ---------------- pass 2: recompute, write attn, O = P.V; K/V dbuf ----------------
  f32x4 oacc[4];
#pragma unroll
  for (int c = 0; c < 4; ++c) oacc[c] = (f32x4){0.f, 0.f, 0.f, 0.f};
  float* arow = attn + ((size_t)bh * Ss + qg) * Ss;

  gl_lds16(kt + c0 * 512 + lane * 8, &S4[c0 * 512]);
  gl_lds16(kt + c1 * 512 + lane * 8, &S4[c1 * 512]);
  gl_lds16(vt + c0 * 512 + lane * 8, &S4[4096 + c0 * 512]);
  gl_lds16(vt + c1 * 512 + lane * 8, &S4[4096 + c1 * 512]);
  asm volatile("s_waitcnt vmcnt(0)" ::: "memory");
  __builtin_amdgcn_s_barrier();
  asm volatile("" ::: "memory");
  for (int j = 0; j <= qt; ++j) {
    const unsigned short* Ksl = &S4[(j & 1) * 8192];
    const unsigned short* Vsl = Ksl + 4096;
    if (j < qt) {  // stage next tile into other slot (loads issued BEFORE any store)
      const unsigned short* ntk = kt + (size_t)(j + 1) * 4096;
      const unsigned short* ntv = vt + (size_t)(j + 1) * 4096;
      unsigned short* d = &S4[((j + 1) & 1) * 8192];
      gl_lds16(ntk + c0 * 512 + lane * 8, d + c0 * 512);
      gl_lds16(ntk + c1 * 512 + lane * 8, d + c1 * 512);
      gl_lds16(ntv + c0 * 512 + lane * 8, d + 4096 + c0 * 512);
      gl_lds16(ntv + c1 * 512 + lane * 8, d + 4096 + c1 * 512);
    }
    asm volatile("" ::: "memory");  // pin: stage loads stay oldest in vmcnt order
    float sv[16];
#pragma unroll
    for (int c = 0; c < 4; ++c) {
      bf16x8 kf0 = *(const bf16x8*)&Ksl[(c * 2 + 0) * 512 + lane * 8];
      bf16x8 kf1 = *(const bf16x8*)&Ksl[(c * 2 + 1) * 512 + lane * 8];
      f32x4 acc = {0.f, 0.f, 0.f, 0.f};
      acc = __builtin_amdgcn_mfma_f32_16x16x32_bf16(kf0, qf0, acc, 0, 0, 0);
      acc = __builtin_amdgcn_mfma_f32_16x16x32_bf16(kf1, qf1, acc, 0, 0, 0);
#pragma unroll
      for (int r = 0; r < 4; ++r) sv[c * 4 + r] = acc[r];
    }
    if (j == qt) {
#pragma unroll
      for (int c = 0; c < 4; ++c)
#pragma unroll
        for (int r = 0; r < 4; ++r)
          if (c * 16 + quad * 4 + r > qloc) sv[c * 4 + r] = NEG;
    }
#pragma unroll
    for (int c = 0; c < 4; ++c) {
      float4 pv;
      pv.x = __expf(sv[c * 4 + 0] - msum);
      pv.y = __expf(sv[c * 4 + 1] - msum);
      pv.z = __expf(sv[c * 4 + 2] - msum);
      pv.w = __expf(sv[c * 4 + 3] - msum);
      *(float4*)&arow[j * 64 + c * 16 + quad * 4] = pv;
      ushort4 u;
      u.x = f2bf(pv.x); u.y = f2bf(pv.y); u.z = f2bf(pv.z); u.w = f2bf(pv.w);
      *(ushort4*)&Plds[PIDX(qloc, c * 16 + quad * 4)] = u;  // own-wave strip only
    }
#pragma unroll
    for (int ch = 0; ch < 2; ++ch) {
      bf16x8 pf = *(const bf16x8*)&Plds[PIDX(qloc, quad * 8 + 32 * ch)];
#pragma unroll
      for (int c = 0; c < 4; ++c) {
        bf16x8 vf = *(const bf16x8*)&Vsl[(c * 2 + ch) * 512 + lane * 8];
        oacc[c] = __builtin_amdgcn_mfma_f32_16x16x32_bf16(vf, pf, oacc[c], 0, 0, 0);
      }
    }
    // counted wait: 4 stage loads (oldest) done; 4 attn stores may stay in flight
    asm volatile("s_waitcnt vmcnt(4)" ::: "memory");
    __builtin_amdgcn_s_barrier();
    asm volatile("" ::: "memory");
  }

  // zero-fill strictly-above-diagonal tiles, coalesced float4
  for (int j = qt + 1; j < 32; ++j) {
    float4 z = {0.f, 0.f, 0.f, 0.f};
#pragma unroll
    for (int i = 0; i < 4; ++i) {
      int idx4 = tid + i * 256;
      int row = idx4 >> 4, col = (idx4 & 15) * 4;
      *(float4*)&attn[((size_t)bh * Ss + qt * 64 + row) * Ss + j * 64 + col] = z;
    }
  }

  // ---- write O ----
#pragma unroll
  for (int c = 0; c < 4; ++c)
    *(f32x4*)&out[((size_t)bh * Ss + qg) * Dd + c * 16 + quad * 4] = oacc[c];
}

// ---------------- fallback (proven round-0 kernel) for masked inputs / no ws ----------------
__global__ __launch_bounds__(256) void attn_kernel_fb(
    const float* __restrict__ q, const float* __restrict__ k,
    const float* __restrict__ v, const int* __restrict__ mask,
    float* __restrict__ out, float* __restrict__ attn,
    const unsigned* __restrict__ flagsM, int force) {
  if (!force && flagsM[0] == 0) return;  // fast path handled it
  const int tid  = threadIdx.x;
  const int wave = tid >> 6;
  const int lane = tid & 63;
  const int quad = lane >> 4;
  const int ln15 = lane & 15;

  const int bh = blockIdx.x & 31;
  const int qt = 31 - (blockIdx.x >> 5);
  const int b  = bh >> 4;

  __shared__ unsigned short Klds[64 * 72];
  __shared__ unsigned short Vlds[64 * 72];
  __shared__ unsigned short Plds2[64 * 72];

  {
    const float* qp = q + ((size_t)bh * Ss + (size_t)qt * 64) * Dd;
#pragma unroll
    for (int i = 0; i < 4; ++i) {
      int idx4 = tid + i * 256;
      int row = idx4 >> 4, col = (idx4 & 15) * 4;
      float4 f = *(const float4*)(qp + row * 64 + col);
      ushort4 u;
      u.x = f2bf(f.x * 0.125f); u.y = f2bf(f.y * 0.125f);
      u.z = f2bf(f.z * 0.125f); u.w = f2bf(f.w * 0.125f);
      *(ushort4*)&Vlds[row * 72 + col] = u;
    }
  }
  __syncthreads();
  const bf16x8 qfrag0 = *(const bf16x8*)&Vlds[(wave * 16 + ln15) * 72 + quad * 8];
  const bf16x8 qfrag1 = *(const bf16x8*)&Vlds[(wave * 16 + ln15) * 72 + quad * 8 + 32];

  float mrow[4], lrow[4];
#pragma unroll
  for (int r = 0; r < 4; ++r) { mrow[r] = -1e30f; lrow[r] = 0.0f; }

  for (int j = 0; j <= qt; ++j) {
    __syncthreads();
    {
      const float* kp = k + ((size_t)bh * Ss + (size_t)j * 64) * Dd;
#pragma unroll
      for (int i = 0; i < 4; ++i) {
        int idx4 = tid + i * 256;
        int row = idx4 >> 4, col = (idx4 & 15) * 4;
        float4 f = *(const float4*)(kp + row * 64 + col);
        ushort4 u;
        u.x = f2bf(f.x); u.y = f2bf(f.y); u.z = f2bf(f.z); u.w = f2bf(f.w);
        *(ushort4*)&Klds[row * 72 + col] = u;
      }
    }
    __syncthreads();
    unsigned long long mm = __ballot(mask[(size_t)b * Ss + j * 64 + lane] != 0);

    float sv[4][4];
#pragma unroll
    for (int c = 0; c < 4; ++c) {
      bf16x8 kf0 = *(const bf16x8*)&Klds[(c * 16 + ln15) * 72 + quad * 8];
      bf16x8 kf1 = *(const bf16x8*)&Klds[(c * 16 + ln15) * 72 + quad * 8 + 32];
      f32x4 acc = {0.f, 0.f, 0.f, 0.f};
      acc = __builtin_amdgcn_mfma_f32_16x16x32_bf16(qfrag0, kf0, acc, 0, 0, 0);
      acc = __builtin_amdgcn_mfma_f32_16x16x32_bf16(qfrag1, kf1, acc, 0, 0, 0);
      int col = j * 64 + c * 16 + ln15;
      bool mz = !((mm >> (c * 16 + ln15)) & 1);
#pragma unroll
      for (int r = 0; r < 4; ++r) {
        int row = qt * 64 + wave * 16 + quad * 4 + r;
        float val = acc[r];
        if (col > row || mz) val = NEG;
        sv[c][r] = val;
      }
    }
#pragma unroll
    for (int r = 0; r < 4; ++r) {
      float tm = fmaxf(fmaxf(sv[0][r], sv[1][r]), fmaxf(sv[2][r], sv[3][r]));
      tm = fmaxf(tm, __shfl_xor(tm, 1));
      tm = fmaxf(tm, __shfl_xor(tm, 2));
      tm = fmaxf(tm, __shfl_xor(tm, 4));
      tm = fmaxf(tm, __shfl_xor(tm, 8));
      float mnew = fmaxf(mrow[r], tm);
      float ss = __expf(sv[0][r] - mnew) + __expf(sv[1][r] - mnew) +
                 __expf(sv[2][r] - mnew) + __expf(sv[3][r] - mnew);
      ss += __shfl_xor(ss, 1);
      ss += __shfl_xor(ss, 2);
      ss += __shfl_xor(ss, 4);
      ss += __shfl_xor(ss, 8);
      lrow[r] = lrow[r] * __expf(mrow[r] - mnew) + ss;
      mrow[r] = mnew;
    }
  }

  float rl4[4];
#pragma unroll
  for (int r = 0; r < 4; ++r) rl4[r] = 1.0f / lrow[r];

  f32x4 oacc[4];
#pragma unroll
  for (int c = 0; c < 4; ++c) oacc[c] = (f32x4){0.f, 0.f, 0.f, 0.f};

  for (int j = 0; j < 32; ++j) {
    if (j <= qt) {
      __syncthreads();
      {
        const float* kp = k + ((size_t)bh * Ss + (size_t)j * 64) * Dd;
        const float* vp = v + ((size_t)bh * Ss + (size_t)j * 64) * Dd;
#pragma unroll
        for (int i = 0; i < 4; ++i) {
          int idx4 = tid + i * 256;
          int row = idx4 >> 4, col = (idx4 & 15) * 4;
          float4 f = *(const float4*)(kp + row * 64 + col);
          ushort4 u;
          u.x = f2bf(f.x); u.y = f2bf(f.y); u.z = f2bf(f.z); u.w = f2bf(f.w);
          *(ushort4*)&Klds[row * 72 + col] = u;
          float4 gg = *(const float4*)(vp + row * 64 + col);
          ushort4 w2;
          w2.x = f2bf(gg.x); w2.y = f2bf(gg.y); w2.z = f2bf(gg.z); w2.w = f2bf(gg.w);
          *(ushort4*)&Vlds[row * 72 + col] = w2;
        }
      }
      __syncthreads();
      unsigned long long mm = __ballot(mask[(size_t)b * Ss + j * 64 + lane] != 0);
#pragma unroll
      for (int c = 0; c < 4; ++c) {
        bf16x8 kf0 = *(const bf16x8*)&Klds[(c * 16 + ln15) * 72 + quad * 8];
        bf16x8 kf1 = *(const bf16x8*)&Klds[(c * 16 + ln15) * 72 + quad * 8 + 32];
        f32x4 acc = {0.f, 0.f, 0.f, 0.f};
        acc = __builtin_amdgcn_mfma_f32_16x16x32_bf16(qfrag0, kf0, acc, 0, 0, 0);
        acc = __builtin_amdgcn_mfma_f32_16x16x32_bf16(qfrag1, kf1, acc, 0, 0, 0);
        int col = j * 64 + c * 16 + ln15;
        bool mz = !((mm >> (c * 16 + ln15)) & 1);
#pragma unroll
        for (int r = 0; r < 4; ++r) {
          int row = qt * 64 + wave * 16 + quad * 4 + r;
          float val = acc[r];
          if (col > row || mz) val = NEG;
          float p = __expf(val - mrow[r]) * rl4[r];
          attn[((size_t)bh * Ss + row) * Ss + col] = p;
          Plds2[(wave * 16 + quad * 4 + r) * 72 + c * 16 + ln15] = f2bf(p);
        }
      }
#pragma unroll
      for (int ch = 0; ch < 2; ++ch) {
        bf16x8 pf = *(const bf16x8*)&Plds2[(wave * 16 + ln15) * 72 + quad * 8 + 32 * ch];
#pragma unroll
        for (int c = 0; c < 4; ++c) {
          bf16x8 vf;
#pragma unroll
          for (int jj = 0; jj < 8; ++jj)
            vf[jj] = (short)Vlds[(quad * 8 + jj + 32 * ch) * 72 + c * 16 + ln15];
          oacc[c] = __builtin_amdgcn_mfma_f32_16x16x32_bf16(pf, vf, oacc[c], 0, 0, 0);
        }
      }
    } else {
      float4 z = {0.f, 0.f, 0.f, 0.f};
#pragma unroll
      for (int i = 0; i < 4; ++i) {
        int idx4 = tid + i * 256;
        int row = idx4 >> 4, col = (idx4 & 15) * 4;
        *(float4*)&attn[((size_t)bh * Ss + qt * 64 + row) * Ss + j * 64 + col] = z;
      }
    }
  }

#pragma unroll
  for (int c = 0; c < 4; ++c)
#pragma unroll
    for (int r = 0; r < 4; ++r) {
      int row = qt * 64 + wave * 16 + quad * 4 + r;
      out[((size_t)bh * Ss + row) * Dd + c * 16 + ln15] = oacc[c][r];
    }
}

extern "C" void kernel_launch(void* const* d_in, const int* in_sizes, int n_in,
                              void* d_out, int out_size, void* d_ws, size_t ws_size,
                              hipStream_t stream) {
  const float* q    = (const float*)d_in[0];
  const float* k    = (const float*)d_in[1];
  const float* v    = (const float*)d_in[2];
  const int*   mask = (const int*)d_in[3];
  float* out  = (float*)d_out;
  float* attn = out + (size_t)2 * 16 * 2048 * 64;  // out first, then attn

  const size_t need = 256 + (size_t)2 * 32 * Ss * Dd * sizeof(unsigned short);
  if (d_ws != nullptr && ws_size >= need) {
    unsigned* flagsM = (unsigned*)d_ws;
    unsigned short* kbf  = (unsigned short*)((char*)d_ws + 256);
    unsigned short* vtbf = kbf + (size_t)32 * Ss * Dd;
    init_kernel<<<dim3(1), dim3(64), 0, stream>>>(flagsM);
    prep_kernel<<<dim3(32 * 32), dim3(256), 0, stream>>>(k, v, mask, kbf, vtbf, flagsM);
    attn_fast<<<dim3(32 * 32), dim3(256), 0, stream>>>(q, kbf, vtbf, flagsM, out, attn);
    attn_kernel_fb<<<dim3(32 * 32), dim3(256), 0, stream>>>(q, k, v, mask, out, attn, flagsM, 0);
  } else {
    attn_kernel_fb<<<dim3(32 * 32), dim3(256), 0, stream>>>(q, k, v, mask, out, attn, nullptr, 1);
  }
}